// Round 2
// baseline (1364.270 us; speedup 1.0000x reference)
//
#include <hip/hip_runtime.h>
#include <math.h>

#define D_   16
#define H_   56
#define W_   56
#define CIN  32
#define COUT 64
#define KPTS 27
#define NCH  81                  // 3*KPTS offset channels
#define NP   (D_*H_*W_)          // 50176 output positions (== 196*256)
#define CHW  (D_*H_*W_)          // per-channel plane size

static __device__ __forceinline__ int iclamp(int v, int lo, int hi) {
    return v < lo ? lo : (v > hi ? hi : v);
}

// ---------------------------------------------------------------------------
// Prep: transpose weights so the innermost (register-unrolled) index is
// contiguous in memory -> uniform s_load runs.
//   weight [COUT][CIN][27taps] -> wT  [tap][c][o]            (o contiguous)
//   offw   [81ch][CIN][27taps] -> owT [tap][c][d][k]         (k contiguous)
//     where original ch = k*3 + d  (k = deform point, d = z/y/x component)
// ---------------------------------------------------------------------------
__global__ __launch_bounds__(256) void k_transpose(const float* __restrict__ w,
                                                   const float* __restrict__ ow,
                                                   float* __restrict__ wT,
                                                   float* __restrict__ owT) {
    int i = blockIdx.x * 256 + threadIdx.x;
    if (i < COUT * CIN * KPTS) {              // [o][c][tap] -> [tap][c][o]
        int tap = i % KPTS;
        int c   = (i / KPTS) % CIN;
        int o   = i / (KPTS * CIN);
        wT[(tap * CIN + c) * COUT + o] = w[i];
    }
    if (i < NCH * CIN * KPTS) {               // [ch][c][tap] -> [tap][c][d][k]
        int tap = i % KPTS;
        int c   = (i / KPTS) % CIN;
        int ch  = i / (KPTS * CIN);
        int d   = ch % 3;
        int k   = ch / 3;
        owT[((tap * CIN + c) * 3 + d) * KPTS + k] = ow[i];
    }
}

// ---------------------------------------------------------------------------
// Kernel A: dense 3x3x3 conv producing offset channels, fused with base-grid
// add. blockIdx.y = d (0=z,1=y,2=x): each thread computes the 27 channels of
// one coordinate component for one position -> acc[27] stays in VGPRs.
// Writes absolute sample coords as [d][k][NP].
// ---------------------------------------------------------------------------
__global__ __launch_bounds__(256) void k_offsets(const float* __restrict__ x,
                                                 const float* __restrict__ owT,
                                                 const float* __restrict__ offb,
                                                 float* __restrict__ coords) {
    const int p  = blockIdx.x * 256 + threadIdx.x;   // grid.x sized exactly
    const int d  = blockIdx.y;                       // 0..2 (uniform per block)
    const int ox = p % W_;
    const int t  = p / W_;
    const int oy = t % H_;
    const int oz = t / H_;

    float acc[KPTS];
#pragma unroll
    for (int k = 0; k < KPTS; ++k) acc[k] = offb[k * 3 + d];

    for (int kz = 0; kz < 3; ++kz) {
        const int  zi = oz - 1 + kz;
        const bool zv = ((unsigned)zi < (unsigned)D_);
        for (int ky = 0; ky < 3; ++ky) {
            const int  yi = oy - 1 + ky;
            const bool yv = ((unsigned)yi < (unsigned)H_);
            for (int kx = 0; kx < 3; ++kx) {
                const int  xi  = ox - 1 + kx;
                const bool v   = zv && yv && ((unsigned)xi < (unsigned)W_);
                const int  tap = (kz * 3 + ky) * 3 + kx;
                const float* xp = x + ((zi * H_ + yi) * W_ + xi);
                const float* wp = owT + (tap * CIN * 3 + d) * KPTS;  // + c*81 + k
                for (int c = 0; c < CIN; ++c) {
                    const float xv = v ? xp[c * CHW] : 0.0f;
#pragma unroll
                    for (int k = 0; k < KPTS; ++k)
                        acc[k] += wp[c * (3 * KPTS) + k] * xv;
                }
            }
        }
    }

    // coords[d][k][p] = offset + base-grid component
    const int bz = oz - 1, by = oy - 1, bx = ox - 1;
#pragma unroll
    for (int k = 0; k < KPTS; ++k) {
        const int kz = k / 9, ky = (k / 3) % 3, kx = k % 3;
        const float base = (d == 0) ? (float)(bz + kz)
                         : (d == 1) ? (float)(by + ky)
                                    : (float)(bx + kx);
        coords[(d * KPTS + k) * NP + p] = acc[k] + base;
    }
}

// ---------------------------------------------------------------------------
// Kernel B: fused trilinear sampling + channel contraction + bias.
// blockIdx.y = g (0/1): each thread computes 32 of the 64 out channels for one
// position -> acc[32] stays in VGPRs. Sampling work duplicated 2x (cheap,
// cache-resident).
// ---------------------------------------------------------------------------
__global__ __launch_bounds__(256) void k_dconv(const float* __restrict__ x,
                                               const float* __restrict__ coords,
                                               const float* __restrict__ wT,
                                               const float* __restrict__ bias,
                                               float* __restrict__ out) {
    const int p = blockIdx.x * 256 + threadIdx.x;
    const int g = blockIdx.y;                        // 0..1 (uniform per block)

    float acc[32];
#pragma unroll
    for (int o = 0; o < 32; ++o) acc[o] = 0.0f;

    for (int k = 0; k < KPTS; ++k) {
        const float cz = coords[(0 * KPTS + k) * NP + p];
        const float cy = coords[(1 * KPTS + k) * NP + p];
        const float cx = coords[(2 * KPTS + k) * NP + p];

        const float zf = floorf(cz), yf = floorf(cy), xf = floorf(cx);
        const float fz = cz - zf, fy = cy - yf, fx = cx - xf;
        const int z0 = (int)zf, y0 = (int)yf, x0 = (int)xf;

        float w8[8];
        int   idx8[8];
#pragma unroll
        for (int j = 0; j < 8; ++j) {
            const int dz = j >> 2, dy = (j >> 1) & 1, dx = j & 1;
            const int zi = z0 + dz, yi = y0 + dy, xi = x0 + dx;
            const bool v = ((unsigned)zi < (unsigned)D_) &&
                           ((unsigned)yi < (unsigned)H_) &&
                           ((unsigned)xi < (unsigned)W_);
            const float wz = dz ? fz : 1.0f - fz;
            const float wy = dy ? fy : 1.0f - fy;
            const float wx = dx ? fx : 1.0f - fx;
            w8[j] = v ? wz * wy * wx : 0.0f;
            const int zc = iclamp(zi, 0, D_ - 1);
            const int yc = iclamp(yi, 0, H_ - 1);
            const int xc = iclamp(xi, 0, W_ - 1);
            idx8[j] = (zc * H_ + yc) * W_ + xc;
        }

        const float* wp = wT + k * CIN * COUT + g * 32;   // + c*64 + o
        for (int c = 0; c < CIN; ++c) {
            const float* xc = x + c * CHW;
            float sv = 0.0f;
#pragma unroll
            for (int j = 0; j < 8; ++j) sv += w8[j] * xc[idx8[j]];
#pragma unroll
            for (int o = 0; o < 32; ++o)
                acc[o] += wp[c * COUT + o] * sv;
        }
    }

#pragma unroll
    for (int o = 0; o < 32; ++o)
        out[(g * 32 + o) * NP + p] = acc[o] + bias[g * 32 + o];
}

// ---------------------------------------------------------------------------
extern "C" void kernel_launch(void* const* d_in, const int* in_sizes, int n_in,
                              void* d_out, int out_size, void* d_ws, size_t ws_size,
                              hipStream_t stream) {
    const float* x    = (const float*)d_in[0];  // [32,16,56,56]
    const float* offw = (const float*)d_in[1];  // [81,32,3,3,3]
    const float* offb = (const float*)d_in[2];  // [81]
    const float* wgt  = (const float*)d_in[3];  // [64,32,3,3,3]
    const float* bias = (const float*)d_in[4];  // [64]
    float* out = (float*)d_out;                 // [64,16,56,56]

    float* ws     = (float*)d_ws;
    float* coords = ws;                         // 3*27*NP floats (~16.3 MB)
    float* wT     = coords + 3 * KPTS * NP;     // 27*32*64
    float* owT    = wT + KPTS * CIN * COUT;     // 27*32*3*27

    const int n_tr = NCH * CIN * KPTS;          // 69984 (covers both transposes)
    hipLaunchKernelGGL(k_transpose, dim3((n_tr + 255) / 256), dim3(256), 0, stream,
                       wgt, offw, wT, owT);
    hipLaunchKernelGGL(k_offsets, dim3(NP / 256, 3), dim3(256), 0, stream,
                       x, owT, offb, coords);
    hipLaunchKernelGGL(k_dconv, dim3(NP / 256, 2), dim3(256), 0, stream,
                       x, coords, wT, bias, out);
}

// Round 5
// 637.188 us; speedup vs baseline: 2.1411x; 2.1411x over previous
//
#include <hip/hip_runtime.h>
#include <math.h>

#define D_   16
#define H_   56
#define W_   56
#define CIN  32
#define COUT 64
#define KPTS 27
#define NCH  81                  // 3*KPTS offset channels
#define NP   (D_*H_*W_)          // 50176 output positions
#define CHW  (D_*H_*W_)          // per-channel plane size

typedef float f4 __attribute__((ext_vector_type(4)));

static __device__ __forceinline__ int iclamp(int v, int lo, int hi) {
    return v < lo ? lo : (v > hi ? hi : v);
}

// ---------------------------------------------------------------------------
// Prep 1: weight transposes (contiguous innermost index for uniform s_loads).
//   weight [COUT][CIN][27taps] -> wT  [tap][c][o]
//   offw   [81ch][CIN][27taps] -> owT [tap][c][d][k]   (ch = k*3 + d)
// ---------------------------------------------------------------------------
__global__ __launch_bounds__(256) void k_prep(const float* __restrict__ w,
                                              const float* __restrict__ ow,
                                              float* __restrict__ wT,
                                              float* __restrict__ owT) {
    int i = blockIdx.x * 256 + threadIdx.x;
    if (i < COUT * CIN * KPTS) {
        int tap = i % KPTS;
        int c   = (i / KPTS) % CIN;
        int o   = i / (KPTS * CIN);
        wT[(tap * CIN + c) * COUT + o] = w[i];
    }
    if (i < NCH * CIN * KPTS) {
        int tap = i % KPTS;
        int c   = (i / KPTS) % CIN;
        int ch  = i / (KPTS * CIN);
        int d   = ch % 3;
        int k   = ch / 3;
        owT[((tap * CIN + c) * 3 + d) * KPTS + k] = ow[i];
    }
}

// ---------------------------------------------------------------------------
// Prep 2: x [c][z][y][x] -> xT [z][y][x][c]  (channels-last, 6.4 MB)
// Reads coalesced per c; writes 8 float4 per thread.
// ---------------------------------------------------------------------------
__global__ __launch_bounds__(64) void k_xT(const float* __restrict__ x,
                                           float* __restrict__ xT) {
    const int s = blockIdx.x * 64 + threadIdx.x;   // spatial index, grid exact
    float r[CIN];
#pragma unroll
    for (int c = 0; c < CIN; ++c) r[c] = x[c * CHW + s];
    f4* dst = (f4*)(xT + (size_t)s * CIN);
#pragma unroll
    for (int cc = 0; cc < 8; ++cc) {
        f4 v;
        v.x = r[cc * 4 + 0]; v.y = r[cc * 4 + 1];
        v.z = r[cc * 4 + 2]; v.w = r[cc * 4 + 3];
        dst[cc] = v;
    }
}

// ---------------------------------------------------------------------------
// Prep 3: out[o][p] = bias[o]  (k_dconv accumulates into it atomically)
// ---------------------------------------------------------------------------
__global__ __launch_bounds__(256) void k_init(const float* __restrict__ bias,
                                              float* __restrict__ out) {
    const int i    = blockIdx.x * 256 + threadIdx.x;  // float4 index
    const int idx4 = i * 4;                           // NP % 4 == 0
    const float b  = bias[idx4 / NP];
    f4 v; v.x = b; v.y = b; v.z = b; v.w = b;
    ((f4*)out)[i] = v;
}

// ---------------------------------------------------------------------------
// Kernel A: dense 3x3x3 conv -> offset channels, fused base-grid add.
// blockIdx.y = d (z/y/x component); each thread: 27 channels of one component
// for one position. Channels-last x: per tap, the 32 input channels are 128
// contiguous bytes -> 8 float4 loads, one latency wait per tap.
// ---------------------------------------------------------------------------
__global__ __launch_bounds__(64, 1) void k_offsets(const float* __restrict__ xT,
                                                   const float* __restrict__ owT,
                                                   const float* __restrict__ offb,
                                                   float* __restrict__ coords) {
    const int p  = blockIdx.x * 64 + threadIdx.x;
    const int d  = blockIdx.y;                       // uniform per block
    const int ox = p % W_;
    const int t  = p / W_;
    const int oy = t % H_;
    const int oz = t / H_;

    float acc[KPTS];
#pragma unroll
    for (int k = 0; k < KPTS; ++k) acc[k] = offb[k * 3 + d];

    for (int tap = 0; tap < KPTS; ++tap) {           // rolled
        const int kz = tap / 9, ky = (tap / 3) % 3, kx = tap % 3;
        const int zi = oz - 1 + kz, yi = oy - 1 + ky, xi = ox - 1 + kx;
        const bool val = ((unsigned)zi < (unsigned)D_) &&
                         ((unsigned)yi < (unsigned)H_) &&
                         ((unsigned)xi < (unsigned)W_);
        const int zc = iclamp(zi, 0, D_ - 1);
        const int yc = iclamp(yi, 0, H_ - 1);
        const int xc = iclamp(xi, 0, W_ - 1);
        const float m = val ? 1.0f : 0.0f;
        const f4* src = (const f4*)(xT + (size_t)((zc * H_ + yc) * W_ + xc) * CIN);

        f4 xv[8];
#pragma unroll
        for (int cc = 0; cc < 8; ++cc) xv[cc] = src[cc];
#pragma unroll
        for (int cc = 0; cc < 8; ++cc) xv[cc] *= m;

        const float* wp = owT + ((size_t)tap * CIN * 3 + d) * KPTS;  // + c*81 + k
#pragma unroll
        for (int cc = 0; cc < 8; ++cc) {
#pragma unroll
            for (int e = 0; e < 4; ++e) {
                const float xs = (e == 0) ? xv[cc].x : (e == 1) ? xv[cc].y
                                : (e == 2) ? xv[cc].z : xv[cc].w;
                const float* wc = wp + (cc * 4 + e) * (3 * KPTS);
#pragma unroll
                for (int k = 0; k < KPTS; ++k) acc[k] += wc[k] * xs;
            }
        }
    }

    const int bz = oz - 1, by = oy - 1, bx = ox - 1;
#pragma unroll
    for (int k = 0; k < KPTS; ++k) {
        const int kz = k / 9, ky = (k / 3) % 3, kx = k % 3;
        const float base = (d == 0) ? (float)(bz + kz)
                         : (d == 1) ? (float)(by + ky)
                                    : (float)(bx + kx);
        coords[(d * KPTS + k) * NP + p] = acc[k] + base;
    }
}

// ---------------------------------------------------------------------------
// Kernel B: fused trilinear sampling + contraction. blockIdx.y = tap group
// (9 taps each); all 64 out-channels accumulate in VGPRs, results added to
// the bias-initialized output via atomicAdd (<=3-way contention).
// ---------------------------------------------------------------------------
__global__ __launch_bounds__(64, 1) void k_dconv(const float* __restrict__ xT,
                                                 const float* __restrict__ coords,
                                                 const float* __restrict__ wT,
                                                 float* __restrict__ out) {
    const int p = blockIdx.x * 64 + threadIdx.x;
    const int g = blockIdx.y;                        // 0..2, taps [9g, 9g+9)

    float acc[COUT];
#pragma unroll
    for (int o = 0; o < COUT; ++o) acc[o] = 0.0f;

    for (int tap = 9 * g; tap < 9 * g + 9; ++tap) {  // rolled
        const float cz = coords[(0 * KPTS + tap) * NP + p];
        const float cy = coords[(1 * KPTS + tap) * NP + p];
        const float cx = coords[(2 * KPTS + tap) * NP + p];

        const float zf = floorf(cz), yf = floorf(cy), xf = floorf(cx);
        const float fz = cz - zf, fy = cy - yf, fx = cx - xf;
        const int z0 = (int)zf, y0 = (int)yf, x0 = (int)xf;

        float w8[8];
        int   base8[8];
#pragma unroll
        for (int j = 0; j < 8; ++j) {
            const int dz = j >> 2, dy = (j >> 1) & 1, dx = j & 1;
            const int zi = z0 + dz, yi = y0 + dy, xi = x0 + dx;
            const bool v = ((unsigned)zi < (unsigned)D_) &&
                           ((unsigned)yi < (unsigned)H_) &&
                           ((unsigned)xi < (unsigned)W_);
            const float wz = dz ? fz : 1.0f - fz;
            const float wy = dy ? fy : 1.0f - fy;
            const float wx = dx ? fx : 1.0f - fx;
            w8[j] = v ? wz * wy * wx : 0.0f;
            const int zc = iclamp(zi, 0, D_ - 1);
            const int yc = iclamp(yi, 0, H_ - 1);
            const int xc = iclamp(xi, 0, W_ - 1);
            base8[j] = ((zc * H_ + yc) * W_ + xc) * CIN;
        }

        const float* wp = wT + (size_t)tap * CIN * COUT;
        for (int cc = 0; cc < 8; ++cc) {             // rolled; body ~2.3 KB
            f4 s; s.x = 0.f; s.y = 0.f; s.z = 0.f; s.w = 0.f;
#pragma unroll
            for (int j = 0; j < 8; ++j) {
                const f4 v = *(const f4*)(xT + base8[j] + cc * 4);
                s += w8[j] * v;
            }
            const float* wq = wp + cc * 4 * COUT;    // uniform -> s_loads
#pragma unroll
            for (int e = 0; e < 4; ++e) {
                const float sv = (e == 0) ? s.x : (e == 1) ? s.y
                                : (e == 2) ? s.z : s.w;
#pragma unroll
                for (int o = 0; o < COUT; ++o)
                    acc[o] += wq[e * COUT + o] * sv;
            }
        }
    }

    float* op = out + p;
#pragma unroll
    for (int o = 0; o < COUT; ++o)
        atomicAdd(op + o * NP, acc[o]);
}

// ---------------------------------------------------------------------------
extern "C" void kernel_launch(void* const* d_in, const int* in_sizes, int n_in,
                              void* d_out, int out_size, void* d_ws, size_t ws_size,
                              hipStream_t stream) {
    const float* x    = (const float*)d_in[0];  // [32,16,56,56]
    const float* offw = (const float*)d_in[1];  // [81,32,3,3,3]
    const float* offb = (const float*)d_in[2];  // [81]
    const float* wgt  = (const float*)d_in[3];  // [64,32,3,3,3]
    const float* bias = (const float*)d_in[4];  // [64]
    float* out = (float*)d_out;                 // [64,16,56,56]

    float* ws     = (float*)d_ws;
    float* coords = ws;                          // 3*27*NP        (~16.3 MB)
    float* wT     = coords + 3 * KPTS * NP;      // 27*32*64
    float* owT    = wT + KPTS * CIN * COUT;      // 27*32*81
    float* xT     = owT + KPTS * CIN * 3 * KPTS; // NP*32          (~6.4 MB)

    const int n_tr = NCH * CIN * KPTS;           // 69984
    hipLaunchKernelGGL(k_prep, dim3((n_tr + 255) / 256), dim3(256), 0, stream,
                       wgt, offw, wT, owT);
    hipLaunchKernelGGL(k_xT, dim3(NP / 64), dim3(64), 0, stream, x, xT);
    hipLaunchKernelGGL(k_init, dim3(COUT * NP / 4 / 256), dim3(256), 0, stream,
                       bias, out);
    hipLaunchKernelGGL(k_offsets, dim3(NP / 64, 3), dim3(64), 0, stream,
                       xT, owT, offb, coords);
    hipLaunchKernelGGL(k_dconv, dim3(NP / 64, 3), dim3(64), 0, stream,
                       xT, coords, wT, out);
}

// Round 8
// 544.873 us; speedup vs baseline: 2.5038x; 1.1694x over previous
//
#include <hip/hip_runtime.h>
#include <math.h>

#define D_   16
#define H_   56
#define W_   56
#define CIN  32
#define COUT 64
#define KPTS 27
#define NCH  81                  // 3*KPTS offset channels
#define NP   (D_*H_*W_)          // 50176 output positions
#define CHW  (D_*H_*W_)          // per-channel plane size
#define KPAD 28                  // 27 deform points padded to f4 multiple

typedef float f4 __attribute__((ext_vector_type(4)));

static __device__ __forceinline__ int iclamp(int v, int lo, int hi) {
    return v < lo ? lo : (v > hi ? hi : v);
}

// ---------------------------------------------------------------------------
// Prep 1: weight transposes.
//   weight [COUT][CIN][27taps]      -> wT  [tap][c][o]          (o contiguous)
//   offw   [81ch][CIN][27taps]      -> owT [tap][d][c][28]      (kpt contiguous,
//     ch = kpt*3 + d; slot 27 zero-padded)
// ---------------------------------------------------------------------------
__global__ __launch_bounds__(256) void k_prep(const float* __restrict__ w,
                                              const float* __restrict__ ow,
                                              float* __restrict__ wT,
                                              float* __restrict__ owT) {
    int i = blockIdx.x * 256 + threadIdx.x;
    if (i < COUT * CIN * KPTS) {
        int tap = i % KPTS;
        int c   = (i / KPTS) % CIN;
        int o   = i / (KPTS * CIN);
        wT[(tap * CIN + c) * COUT + o] = w[i];
    }
    if (i < NCH * CIN * KPTS) {
        int tap = i % KPTS;
        int c   = (i / KPTS) % CIN;
        int ch  = i / (KPTS * CIN);
        int d   = ch % 3;
        int kpt = ch / 3;
        owT[(((tap * 3) + d) * CIN + c) * KPAD + kpt] = ow[i];
    }
    if (i < KPTS * 3 * CIN)                      // zero the pad slot
        owT[i * KPAD + 27] = 0.0f;
}

// ---------------------------------------------------------------------------
// Prep 2: x [c][z][y][x] -> xT [z][y][x][c]  (channels-last, 6.4 MB)
// ---------------------------------------------------------------------------
__global__ __launch_bounds__(64) void k_xT(const float* __restrict__ x,
                                           float* __restrict__ xT) {
    const int s = blockIdx.x * 64 + threadIdx.x;
    float r[CIN];
#pragma unroll
    for (int c = 0; c < CIN; ++c) r[c] = x[c * CHW + s];
    f4* dst = (f4*)(xT + (size_t)s * CIN);
#pragma unroll
    for (int cc = 0; cc < 8; ++cc) {
        f4 v;
        v.x = r[cc * 4 + 0]; v.y = r[cc * 4 + 1];
        v.z = r[cc * 4 + 2]; v.w = r[cc * 4 + 3];
        dst[cc] = v;
    }
}

// ---------------------------------------------------------------------------
// Prep 3: out[o][p] = bias[o]  (k_dconv accumulates into it atomically)
// ---------------------------------------------------------------------------
__global__ __launch_bounds__(256) void k_init(const float* __restrict__ bias,
                                              float* __restrict__ out) {
    const int i   = blockIdx.x * 256 + threadIdx.x;  // float4 index
    const float b = bias[(i * 4) / NP];              // NP % 4 == 0
    f4 v; v.x = b; v.y = b; v.z = b; v.w = b;
    ((f4*)out)[i] = v;
}

// ---------------------------------------------------------------------------
// Kernel A: dense 3x3x3 conv -> offset channels, fused base-grid add.
// blockIdx.y = d. 27(+1 pad) accumulators in NAMED f4 registers A0..A6.
// Per-tap weight slice [c][28] staged in LDS; uniform ds_read broadcasts.
// ---------------------------------------------------------------------------
__global__ __launch_bounds__(64, 2) void k_offsets(const float* __restrict__ xT,
                                                   const float* __restrict__ owT,
                                                   const float* __restrict__ offb,
                                                   float* __restrict__ coords) {
    __shared__ __align__(16) float lw[CIN * KPAD];   // 896 floats, 3.5 KB
    const int tid = threadIdx.x;
    const int p   = blockIdx.x * 64 + tid;
    const int d   = blockIdx.y;                      // uniform per block
    const int ox  = p % W_;
    const int t   = p / W_;
    const int oy  = t % H_;
    const int oz  = t / H_;

    f4 A0, A1, A2, A3, A4, A5, A6;
#define INIT4(Ai, kb) { f4 v; \
    v.x = offb[((kb) + 0) * 3 + d]; \
    v.y = offb[((kb) + 1) * 3 + d]; \
    v.z = offb[((kb) + 2) * 3 + d]; \
    v.w = ((kb) + 3 < KPTS) ? offb[((kb) + 3) * 3 + d] : 0.0f; \
    Ai = v; }
    INIT4(A0, 0) INIT4(A1, 4) INIT4(A2, 8) INIT4(A3, 12)
    INIT4(A4, 16) INIT4(A5, 20) INIT4(A6, 24)
#undef INIT4

    for (int tap = 0; tap < KPTS; ++tap) {
        __syncthreads();                             // prior reads done
        {   // stage weight slice for (tap, d): 224 f4, coalesced
            const f4* src4 = (const f4*)(owT + (size_t)((tap * 3 + d) * CIN) * KPAD);
            f4* lw4 = (f4*)lw;
            for (int q = tid; q < CIN * KPAD / 4; q += 64) lw4[q] = src4[q];
        }
        __syncthreads();

        const int kz = tap / 9, ky = (tap / 3) % 3, kx = tap % 3;
        const int zi = oz - 1 + kz, yi = oy - 1 + ky, xi = ox - 1 + kx;
        const bool val = ((unsigned)zi < (unsigned)D_) &&
                         ((unsigned)yi < (unsigned)H_) &&
                         ((unsigned)xi < (unsigned)W_);
        const int zc = iclamp(zi, 0, D_ - 1);
        const int yc = iclamp(yi, 0, H_ - 1);
        const int xc = iclamp(xi, 0, W_ - 1);
        const float m = val ? 1.0f : 0.0f;
        const f4* src = (const f4*)(xT + (size_t)((zc * H_ + yc) * W_ + xc) * CIN);

        f4 X0 = src[0] * m, X1 = src[1] * m, X2 = src[2] * m, X3 = src[3] * m;
        f4 X4 = src[4] * m, X5 = src[5] * m, X6 = src[6] * m, X7 = src[7] * m;

        const f4* lw4 = (const f4*)lw;
#define OF(xs, cfull) { const float s_ = (xs); const f4* wp = lw4 + (cfull) * 7; \
    A0 += wp[0] * s_; A1 += wp[1] * s_; A2 += wp[2] * s_; A3 += wp[3] * s_; \
    A4 += wp[4] * s_; A5 += wp[5] * s_; A6 += wp[6] * s_; }
#define OCC(Xi, cc) { OF(Xi.x, (cc)*4+0) OF(Xi.y, (cc)*4+1) \
                      OF(Xi.z, (cc)*4+2) OF(Xi.w, (cc)*4+3) }
        OCC(X0, 0) OCC(X1, 1) OCC(X2, 2) OCC(X3, 3)
        OCC(X4, 4) OCC(X5, 5) OCC(X6, 6) OCC(X7, 7)
#undef OCC
#undef OF
    }

    // coords[d][kpt][p] = offset + base-grid component
#define BASEF(kk) ((d == 0) ? (float)(oz - 1 + (kk) / 9) \
                 : (d == 1) ? (float)(oy - 1 + ((kk) / 3) % 3) \
                            : (float)(ox - 1 + (kk) % 3))
#define WOUT(Ai, kb) { \
    coords[(d * KPTS + (kb) + 0) * NP + p] = Ai.x + BASEF((kb) + 0); \
    coords[(d * KPTS + (kb) + 1) * NP + p] = Ai.y + BASEF((kb) + 1); \
    coords[(d * KPTS + (kb) + 2) * NP + p] = Ai.z + BASEF((kb) + 2); \
    if ((kb) + 3 < KPTS) \
        coords[(d * KPTS + (kb) + 3) * NP + p] = Ai.w + BASEF((kb) + 3); }
    WOUT(A0, 0) WOUT(A1, 4) WOUT(A2, 8) WOUT(A3, 12)
    WOUT(A4, 16) WOUT(A5, 20) WOUT(A6, 24)
#undef WOUT
#undef BASEF
}

// ---------------------------------------------------------------------------
// Kernel B: fused trilinear sampling + contraction. blockIdx.y = tap group
// (9 taps). 64 out-channels in NAMED f4 registers A0..A15; per-tap weight
// slice [c][o] (8 KB) staged in LDS, uniform ds_read broadcast.
// ---------------------------------------------------------------------------
__global__ __launch_bounds__(64, 2) void k_dconv(const float* __restrict__ xT,
                                                 const float* __restrict__ coords,
                                                 const float* __restrict__ wT,
                                                 float* __restrict__ out) {
    __shared__ __align__(16) float lw[CIN * COUT];   // 2048 floats = 8 KB
    const int tid = threadIdx.x;
    const int p   = blockIdx.x * 64 + tid;
    const int g   = blockIdx.y;                      // 0..2, taps [9g, 9g+9)

    f4 A0 = 0, A1 = 0, A2 = 0, A3 = 0, A4 = 0, A5 = 0, A6 = 0, A7 = 0;
    f4 A8 = 0, A9 = 0, A10 = 0, A11 = 0, A12 = 0, A13 = 0, A14 = 0, A15 = 0;

    for (int tap = 9 * g; tap < 9 * g + 9; ++tap) {
        __syncthreads();                             // prior reads done
        {   // stage weight slice [32c][64o]: 512 f4, coalesced
            const f4* s4 = (const f4*)(wT + (size_t)tap * CIN * COUT);
            f4* l4 = (f4*)lw;
#pragma unroll
            for (int q0 = 0; q0 < 8; ++q0) l4[q0 * 64 + tid] = s4[q0 * 64 + tid];
        }
        __syncthreads();

        const float cz = coords[(0 * KPTS + tap) * NP + p];
        const float cy = coords[(1 * KPTS + tap) * NP + p];
        const float cx = coords[(2 * KPTS + tap) * NP + p];

        const float zf = floorf(cz), yf = floorf(cy), xf = floorf(cx);
        const float fz = cz - zf, fy = cy - yf, fx = cx - xf;
        const int z0 = (int)zf, y0 = (int)yf, x0 = (int)xf;

        float cw0, cw1, cw2, cw3, cw4, cw5, cw6, cw7;
        int   cb0, cb1, cb2, cb3, cb4, cb5, cb6, cb7;
#define CORNER(jj, Wj, Bj) { \
    const int dz_ = (jj) >> 2, dy_ = ((jj) >> 1) & 1, dx_ = (jj) & 1; \
    const int zi_ = z0 + dz_, yi_ = y0 + dy_, xi_ = x0 + dx_; \
    const bool v_ = ((unsigned)zi_ < (unsigned)D_) && \
                    ((unsigned)yi_ < (unsigned)H_) && \
                    ((unsigned)xi_ < (unsigned)W_); \
    const float wz_ = dz_ ? fz : 1.0f - fz; \
    const float wy_ = dy_ ? fy : 1.0f - fy; \
    const float wx_ = dx_ ? fx : 1.0f - fx; \
    Wj = v_ ? wz_ * wy_ * wx_ : 0.0f; \
    Bj = ((iclamp(zi_, 0, D_ - 1) * H_ + iclamp(yi_, 0, H_ - 1)) * W_ \
          + iclamp(xi_, 0, W_ - 1)) * CIN; }
        CORNER(0, cw0, cb0) CORNER(1, cw1, cb1) CORNER(2, cw2, cb2)
        CORNER(3, cw3, cb3) CORNER(4, cw4, cb4) CORNER(5, cw5, cb5)
        CORNER(6, cw6, cb6) CORNER(7, cw7, cb7)
#undef CORNER

        const f4* l4 = (const f4*)lw;
#define LDX(Bj, cc) (*(const f4*)(xT + (Bj) + (cc) * 4))
#define SFMA(sv, eidx, cc) { const float s_ = (sv); \
    const f4* wq = l4 + (((cc) * 4 + (eidx)) * 16); \
    A0  += wq[0]  * s_; A1  += wq[1]  * s_; A2  += wq[2]  * s_; A3  += wq[3]  * s_; \
    A4  += wq[4]  * s_; A5  += wq[5]  * s_; A6  += wq[6]  * s_; A7  += wq[7]  * s_; \
    A8  += wq[8]  * s_; A9  += wq[9]  * s_; A10 += wq[10] * s_; A11 += wq[11] * s_; \
    A12 += wq[12] * s_; A13 += wq[13] * s_; A14 += wq[14] * s_; A15 += wq[15] * s_; }
#define CCBLK(cc) { \
    f4 s = cw0 * LDX(cb0, cc); \
    s += cw1 * LDX(cb1, cc);  s += cw2 * LDX(cb2, cc); \
    s += cw3 * LDX(cb3, cc);  s += cw4 * LDX(cb4, cc); \
    s += cw5 * LDX(cb5, cc);  s += cw6 * LDX(cb6, cc); \
    s += cw7 * LDX(cb7, cc); \
    SFMA(s.x, 0, cc) SFMA(s.y, 1, cc) SFMA(s.z, 2, cc) SFMA(s.w, 3, cc) }
        CCBLK(0) CCBLK(1) CCBLK(2) CCBLK(3)
        CCBLK(4) CCBLK(5) CCBLK(6) CCBLK(7)
#undef CCBLK
#undef SFMA
#undef LDX
    }

    float* op = out + p;
#define AOUT(Ai, ob) { \
    atomicAdd(op + ((ob) + 0) * NP, Ai.x); atomicAdd(op + ((ob) + 1) * NP, Ai.y); \
    atomicAdd(op + ((ob) + 2) * NP, Ai.z); atomicAdd(op + ((ob) + 3) * NP, Ai.w); }
    AOUT(A0, 0)  AOUT(A1, 4)  AOUT(A2, 8)   AOUT(A3, 12)
    AOUT(A4, 16) AOUT(A5, 20) AOUT(A6, 24)  AOUT(A7, 28)
    AOUT(A8, 32) AOUT(A9, 36) AOUT(A10, 40) AOUT(A11, 44)
    AOUT(A12, 48) AOUT(A13, 52) AOUT(A14, 56) AOUT(A15, 60)
#undef AOUT
}

// ---------------------------------------------------------------------------
extern "C" void kernel_launch(void* const* d_in, const int* in_sizes, int n_in,
                              void* d_out, int out_size, void* d_ws, size_t ws_size,
                              hipStream_t stream) {
    const float* x    = (const float*)d_in[0];  // [32,16,56,56]
    const float* offw = (const float*)d_in[1];  // [81,32,3,3,3]
    const float* offb = (const float*)d_in[2];  // [81]
    const float* wgt  = (const float*)d_in[3];  // [64,32,3,3,3]
    const float* bias = (const float*)d_in[4];  // [64]
    float* out = (float*)d_out;                 // [64,16,56,56]

    float* ws     = (float*)d_ws;
    float* coords = ws;                            // 3*27*NP       (~16.3 MB)
    float* wT     = coords + 3 * KPTS * NP;        // 27*32*64
    float* owT    = wT + KPTS * CIN * COUT;        // 27*3*32*28
    float* xT     = owT + KPTS * 3 * CIN * KPAD;   // NP*32         (~6.4 MB)

    const int n_tr = NCH * CIN * KPTS;             // 69984
    hipLaunchKernelGGL(k_prep, dim3((n_tr + 255) / 256), dim3(256), 0, stream,
                       wgt, offw, wT, owT);
    hipLaunchKernelGGL(k_xT, dim3(NP / 64), dim3(64), 0, stream, x, xT);
    hipLaunchKernelGGL(k_init, dim3(COUT * NP / 4 / 256), dim3(256), 0, stream,
                       bias, out);
    hipLaunchKernelGGL(k_offsets, dim3(NP / 64, 3), dim3(64), 0, stream,
                       xT, owT, offb, coords);
    hipLaunchKernelGGL(k_dconv, dim3(NP / 64, 3), dim3(64), 0, stream,
                       xT, coords, wT, out);
}